// Round 2
// baseline (1148.708 us; speedup 1.0000x reference)
//
#include <hip/hip_runtime.h>

typedef unsigned short ushort_t;
typedef __attribute__((ext_vector_type(8))) short bf16x8;
typedef __attribute__((ext_vector_type(4))) float f32x4;

static constexpr long kN = 16, kC = 512, kHW = 4096;

// ---- workspace layout (bytes) ----
static constexpr size_t OFF_XBF  = 0;
static constexpr size_t OFF_XBFT = OFF_XBF  + (size_t)kN*kC*kHW*2;   // 64 MiB
static constexpr size_t OFF_S    = OFF_XBFT + (size_t)kN*kC*kHW*2;   // 128 MiB
static constexpr size_t OFF_WRB  = OFF_S    + (size_t)kN*kC*4;
static constexpr size_t OFF_WVT  = OFF_WRB  + (size_t)kC*kC*2;
static constexpr size_t OFF_WKT  = OFF_WVT  + (size_t)kC*kC*2;
static constexpr size_t OFF_WQT  = OFF_WKT  + (size_t)kC*kC*2;
static constexpr size_t OFF_wv   = OFF_WQT  + (size_t)kC*kC*2;
static constexpr size_t OFF_v2   = OFF_wv   + 2048;
static constexpr size_t OFF_u3   = OFF_v2   + 2048;
static constexpr size_t OFF_beta = OFF_u3   + 2048;
static constexpr size_t OFF_U    = OFF_beta + 256;
static constexpr size_t OFF_UBF  = OFF_U    + (size_t)kC*kC*4;
static constexpr size_t OFF_VT   = OFF_UBF  + (size_t)kC*kC*2;
static constexpr size_t OFF_VTBF = OFF_VT   + (size_t)kC*kC*4;
static constexpr size_t OFF_G    = OFF_VTBF + (size_t)kC*kC*2;
static constexpr size_t OFF_GBF  = OFF_G    + (size_t)kN*kC*kC*4;
static constexpr size_t OFF_TBF  = OFF_GBF  + (size_t)kN*kC*kC*2;
static constexpr size_t OFF_MBF  = OFF_TBF  + (size_t)kN*kC*kC*2;
static constexpr size_t OFF_u2   = OFF_MBF  + (size_t)kN*kC*kC*2;
static constexpr size_t OFF_v3   = OFF_u2   + (size_t)kN*kC*4;
static constexpr size_t OFF_c    = OFF_v3   + (size_t)kN*kC*4;

static __device__ __forceinline__ ushort_t f2bf(float f) {
  union { float f; unsigned u; } x; x.f = f;
  unsigned r = x.u + 0x7fffu + ((x.u >> 16) & 1u);
  return (ushort_t)(r >> 16);
}

static __device__ __forceinline__ float wred(float a) {
  a += __shfl_xor(a, 32); a += __shfl_xor(a, 16); a += __shfl_xor(a, 8);
  a += __shfl_xor(a, 4);  a += __shfl_xor(a, 2);  a += __shfl_xor(a, 1);
  return a;
}

#define ASYNC16(g, l) __builtin_amdgcn_global_load_lds( \
    (const __attribute__((address_space(1))) void*)(g), \
    (__attribute__((address_space(3))) void*)(l), 16, 0, 0)

// ---- X fp32 -> Xbf [C][HW], XbfT [HW][C] (bf16), row sums s ----
__global__ __launch_bounds__(256) void cvt_kernel(
    const float* __restrict__ X, ushort_t* __restrict__ Xbf,
    ushort_t* __restrict__ XbfT, float* __restrict__ s) {
  __shared__ ushort_t tile[64][80];
  const int n = blockIdx.z, cb = blockIdx.y << 6, mb = blockIdx.x << 6;
  const int t = threadIdx.x;
  const int r = t >> 2, c0 = (t & 3) << 4;
  const long base = ((long)(n * 512 + cb + r)) << 12;  // *4096
  const float4* sp = (const float4*)(X + base + mb + c0);
  __align__(16) float fb[16];
  *(float4*)&fb[0]  = sp[0]; *(float4*)&fb[4]  = sp[1];
  *(float4*)&fb[8]  = sp[2]; *(float4*)&fb[12] = sp[3];
  float sum = 0.f;
  __align__(16) ushort_t ub[16];
#pragma unroll
  for (int e = 0; e < 16; ++e) { sum += fb[e]; ub[e] = f2bf(fb[e]); }
  sum += __shfl_xor(sum, 1); sum += __shfl_xor(sum, 2);
  if ((t & 3) == 0) atomicAdd(&s[n * 512 + cb + r], sum);
  ushort_t* dX = Xbf + base + mb + c0;
  *(uint4*)dX = *(const uint4*)&ub[0];
  *(uint4*)(dX + 8) = *(const uint4*)&ub[8];
  *(uint4*)&tile[r][c0] = *(const uint4*)&ub[0];
  *(uint4*)&tile[r][c0 + 8] = *(const uint4*)&ub[8];
  __syncthreads();
  const int mr = t >> 2, cc = (t & 3) << 4;
  __align__(16) ushort_t ob[16];
#pragma unroll
  for (int i = 0; i < 16; ++i) ob[i] = tile[cc + i][mr];
  ushort_t* dT = XbfT + ((long)n * 4096 + mb + mr) * 512 + cb + cc;
  *(uint4*)dT = *(const uint4*)&ob[0];
  *(uint4*)(dT + 8) = *(const uint4*)&ob[8];
}

// ---- weights: Wr->bf16 copy; Wv,Wk,Wq -> transposed bf16 ----
__global__ __launch_bounds__(256) void prep_weights(
    const float* __restrict__ Wr, const float* __restrict__ Wv,
    const float* __restrict__ Wk, const float* __restrict__ Wq,
    ushort_t* __restrict__ WrB, ushort_t* __restrict__ WvT,
    ushort_t* __restrict__ WkT, ushort_t* __restrict__ WqT) {
  __shared__ float tile[64][65];
  const int z = blockIdx.z, t = threadIdx.x;
  const float* src = (z == 0) ? Wr : (z == 1) ? Wv : (z == 2) ? Wk : Wq;
  ushort_t* dst    = (z == 0) ? WrB : (z == 1) ? WvT : (z == 2) ? WkT : WqT;
  const int r = t >> 2, c0 = (t & 3) << 4;
  const int gr = (blockIdx.y << 6) + r, gc0 = (blockIdx.x << 6) + c0;
  const float4* sp = (const float4*)(src + gr * 512 + gc0);
  __align__(16) float fb[16];
  *(float4*)&fb[0]  = sp[0]; *(float4*)&fb[4]  = sp[1];
  *(float4*)&fb[8]  = sp[2]; *(float4*)&fb[12] = sp[3];
  if (z == 0) {
    __align__(16) ushort_t ub[16];
#pragma unroll
    for (int e = 0; e < 16; ++e) ub[e] = f2bf(fb[e]);
    ushort_t* d = dst + gr * 512 + gc0;
    *(uint4*)d = *(const uint4*)&ub[0];
    *(uint4*)(d + 8) = *(const uint4*)&ub[8];
  } else {
#pragma unroll
    for (int e = 0; e < 16; ++e) tile[r][c0 + e] = fb[e];
    __syncthreads();
    const int mr = t >> 2, k0 = (t & 3) << 4;
    __align__(16) ushort_t ub[16];
#pragma unroll
    for (int i = 0; i < 16; ++i) ub[i] = f2bf(tile[k0 + i][mr]);
    ushort_t* d = dst + ((blockIdx.x << 6) + mr) * 512 + (blockIdx.y << 6) + k0;
    *(uint4*)d = *(const uint4*)&ub[0];
    *(uint4*)(d + 8) = *(const uint4*)&ub[8];
  }
}

// ---- fixed vectors: w = Wk^T bq, v2 = Wq^T bk, u3 = Wr bv, beta = bk.bq ----
__global__ __launch_bounds__(512) void prep_vectors(
    const float* __restrict__ Wk, const float* __restrict__ Wq,
    const float* __restrict__ Wr, const float* __restrict__ bv,
    const float* __restrict__ bk, const float* __restrict__ bq,
    float* __restrict__ w, float* __restrict__ v2,
    float* __restrict__ u3, float* __restrict__ beta) {
  const int z = blockIdx.x, t = threadIdx.x;
  if (z == 0) {
    float a = 0; for (int k = 0; k < 512; ++k) a += Wk[k * 512 + t] * bq[k];
    w[t] = a;
  } else if (z == 1) {
    float a = 0; for (int k = 0; k < 512; ++k) a += Wq[k * 512 + t] * bk[k];
    v2[t] = a;
  } else if (z == 2) {
    float a = 0; for (int k = 0; k < 512; ++k) a += Wr[t * 512 + k] * bv[k];
    u3[t] = a;
  } else {
    __shared__ float red[512];
    red[t] = bk[t] * bq[t];
    __syncthreads();
    for (int st = 256; st; st >>= 1) { if (t < st) red[t] += red[t + st]; __syncthreads(); }
    if (t == 0) beta[0] = red[0];
  }
}

// ---- per-batch vectors: u2 = U s, v3 = VT s, c = (U G w + b u2 + (s.w) u3)/HW + b u3 + br ----
__global__ __launch_bounds__(512) void batch_vectors(
    const float* __restrict__ U, const float* __restrict__ VT,
    const float* __restrict__ G, const float* __restrict__ s,
    const float* __restrict__ w, const float* __restrict__ u3,
    const float* __restrict__ beta, const float* __restrict__ br,
    float* __restrict__ u2, float* __restrict__ v3, float* __restrict__ cvec) {
  const int n = blockIdx.x, t = threadIdx.x, wv = t >> 6, ln = t & 63;
  __shared__ float g1[512], u2l[512], sred[1];
  const float* Gn = G + (long)n * 512 * 512;
  const float* sn = s + n * 512;
  for (int r = wv; r < 1536; r += 8) {
    const int task = r >> 9, row = r & 511;
    const float* mat; const float* vec;
    if (task == 0) { mat = U + row * 512; vec = sn; }
    else if (task == 1) { mat = VT + row * 512; vec = sn; }
    else { mat = Gn + row * 512; vec = w; }
    float a = 0;
    for (int j = ln; j < 512; j += 64) a += mat[j] * vec[j];
    a = wred(a);
    if (ln == 0) {
      if (task == 0) { u2[n * 512 + row] = a; u2l[row] = a; }
      else if (task == 1) v3[n * 512 + row] = a;
      else g1[row] = a;
    }
  }
  if (wv == 0) {
    float a = 0;
    for (int j = ln; j < 512; j += 64) a += sn[j] * w[j];
    a = wred(a);
    if (ln == 0) sred[0] = a;
  }
  __syncthreads();
  const float sw = sred[0], bet = beta[0];
  for (int row = wv; row < 512; row += 8) {
    const float* mat = U + row * 512;
    float a = 0;
    for (int j = ln; j < 512; j += 64) a += mat[j] * g1[j];
    a = wred(a);
    if (ln == 0)
      cvec[n * 512 + row] = (a + bet * u2l[row] + sw * u3[row]) * (1.0f / 4096.0f)
                            + bet * u3[row] + br[row];
  }
}

// ---- fp32 -> bf16 elementwise ----
__global__ __launch_bounds__(256) void cvt_f2b(
    const float* __restrict__ src, ushort_t* __restrict__ dst, int n4) {
  const int i = blockIdx.x * 256 + threadIdx.x;
  if (i >= n4) return;
  const float4 v = ((const float4*)src)[i];
  union { ushort_t u[4]; uint2 q; } o;
  o.u[0] = f2bf(v.x); o.u[1] = f2bf(v.y); o.u[2] = f2bf(v.z); o.u[3] = f2bf(v.w);
  ((uint2*)dst)[i] = o.q;
}

// ---- generic NT GEMM: D[i,j] = sum_k A[i,k]*B[j,k], 128x128x64 tiles ----
enum { EPI_BOTH = 0, EPI_ATOMIC = 1, EPI_BF16 = 2, EPI_RANK1 = 3, EPI_OUT = 4 };

template <int EPI>
__global__ __launch_bounds__(256) void gemm_nt(
    const ushort_t* __restrict__ A, const ushort_t* __restrict__ B,
    float* __restrict__ outF, ushort_t* __restrict__ outB,
    int K, int lda, int ldb, int ldc,
    long sA, long sB, long sC, int kchunks, float alpha,
    const float* __restrict__ eu2, const float* __restrict__ ev2,
    const float* __restrict__ eu3, const float* __restrict__ ev3,
    const float* __restrict__ ec) {
  __shared__ __align__(16) ushort_t As[128 * 64];
  __shared__ __align__(16) ushort_t Bs[128 * 64];
  const int z = blockIdx.z;
  const int batch = z / kchunks, kc = z - batch * kchunks;
  const int bm = blockIdx.y << 7, bn = blockIdx.x << 7;
  const ushort_t* Ab = A + (long)batch * sA + (long)bm * lda + (long)kc * K;
  const ushort_t* Bb = B + (long)batch * sB + (long)bn * ldb + (long)kc * K;
  const int tid = threadIdx.x;
  const int wave = tid >> 6, lane = tid & 63;
  const int wr = wave >> 1, wc = wave & 1;
  const int srow = lane >> 3;
  const int scol = (lane & 7) << 3;
  f32x4 acc[4][4];
  const f32x4 z4 = {0.f, 0.f, 0.f, 0.f};
#pragma unroll
  for (int i = 0; i < 4; ++i)
#pragma unroll
    for (int j = 0; j < 4; ++j) acc[i][j] = z4;

  for (int kt = 0; kt < K; kt += 64) {
#pragma unroll
    for (int p = 0; p < 4; ++p) {
      const int rbase = (p << 5) + (wave << 3);
      ASYNC16(Ab + (long)(rbase + srow) * lda + kt + scol, &As[rbase << 6]);
      ASYNC16(Bb + (long)(rbase + srow) * ldb + kt + scol, &Bs[rbase << 6]);
    }
    __syncthreads();
    const int fr = lane & 15, kg = lane >> 4;
#pragma unroll
    for (int ks = 0; ks < 2; ++ks) {
      bf16x8 av[4], bv[4];
#pragma unroll
      for (int i = 0; i < 4; ++i)
        av[i] = *(const bf16x8*)&As[((wr << 6) + (i << 4) + fr) * 64 + (ks << 5) + (kg << 3)];
#pragma unroll
      for (int j = 0; j < 4; ++j)
        bv[j] = *(const bf16x8*)&Bs[((wc << 6) + (j << 4) + fr) * 64 + (ks << 5) + (kg << 3)];
#pragma unroll
      for (int i = 0; i < 4; ++i)
#pragma unroll
        for (int j = 0; j < 4; ++j)
          acc[i][j] = __builtin_amdgcn_mfma_f32_16x16x32_bf16(av[i], bv[j], acc[i][j], 0, 0, 0);
    }
    __syncthreads();
  }

  const int fr = lane & 15, rg = lane >> 4;
  const float* eu2b = (EPI == EPI_RANK1) ? eu2 + (batch << 9) : nullptr;
  const float* ev3b = (EPI == EPI_RANK1) ? ev3 + (batch << 9) : nullptr;
  const float* ecb  = (EPI == EPI_OUT)   ? ec  + (batch << 9) : nullptr;
#pragma unroll
  for (int i = 0; i < 4; ++i) {
#pragma unroll
    for (int j = 0; j < 4; ++j) {
      const int col = bn + (wc << 6) + (j << 4) + fr;
#pragma unroll
      for (int q = 0; q < 4; ++q) {
        const int row = bm + (wr << 6) + (i << 4) + (rg << 2) + q;
        float val = acc[i][j][q];
        const long off = (long)batch * sC + (long)row * ldc + col;
        if (EPI == EPI_ATOMIC) {
          atomicAdd(&outF[off], val);
        } else if (EPI == EPI_BOTH) {
          outF[off] = val; outB[off] = f2bf(val);
        } else if (EPI == EPI_BF16) {
          outB[off] = f2bf(val);
        } else if (EPI == EPI_RANK1) {
          val = val * alpha + (eu2b[row] * ev2[col] + eu3[row] * ev3b[col]) * alpha
                + eu3[row] * ev2[col];
          outB[off] = f2bf(val);
        } else {
          outF[off] = val + ecb[row];
        }
      }
    }
  }
}

extern "C" void kernel_launch(void* const* d_in, const int* in_sizes, int n_in,
                              void* d_out, int out_size, void* d_ws, size_t ws_size,
                              hipStream_t stream) {
  const float* X  = (const float*)d_in[0];
  const float* Wv = (const float*)d_in[1];
  const float* bv = (const float*)d_in[2];
  const float* Wk = (const float*)d_in[3];
  const float* bk = (const float*)d_in[4];
  const float* Wq = (const float*)d_in[5];
  const float* bq = (const float*)d_in[6];
  const float* Wr = (const float*)d_in[7];
  const float* br = (const float*)d_in[8];
  float* out = (float*)d_out;
  char* ws = (char*)d_ws;

  ushort_t* Xbf  = (ushort_t*)(ws + OFF_XBF);
  ushort_t* XbfT = (ushort_t*)(ws + OFF_XBFT);
  float*    sbuf = (float*)(ws + OFF_S);
  ushort_t* WrB  = (ushort_t*)(ws + OFF_WRB);
  ushort_t* WvT  = (ushort_t*)(ws + OFF_WVT);
  ushort_t* WkT  = (ushort_t*)(ws + OFF_WKT);
  ushort_t* WqT  = (ushort_t*)(ws + OFF_WQT);
  float*    wv_  = (float*)(ws + OFF_wv);
  float*    v2   = (float*)(ws + OFF_v2);
  float*    u3   = (float*)(ws + OFF_u3);
  float*    beta = (float*)(ws + OFF_beta);
  float*    Uf   = (float*)(ws + OFF_U);
  ushort_t* Ubf  = (ushort_t*)(ws + OFF_UBF);
  float*    VTf  = (float*)(ws + OFF_VT);
  ushort_t* VTbf = (ushort_t*)(ws + OFF_VTBF);
  float*    Gf   = (float*)(ws + OFF_G);
  ushort_t* Gbf  = (ushort_t*)(ws + OFF_GBF);
  ushort_t* Tbf  = (ushort_t*)(ws + OFF_TBF);
  ushort_t* Mbf  = (ushort_t*)(ws + OFF_MBF);
  float*    u2   = (float*)(ws + OFF_u2);
  float*    v3   = (float*)(ws + OFF_v3);
  float*    cvec = (float*)(ws + OFF_c);

  hipMemsetAsync(sbuf, 0, (size_t)kN * kC * 4, stream);
  hipMemsetAsync(Gf, 0, (size_t)kN * kC * kC * 4, stream);

  cvt_kernel<<<dim3(64, 8, 16), 256, 0, stream>>>(X, Xbf, XbfT, sbuf);
  prep_weights<<<dim3(8, 8, 4), 256, 0, stream>>>(Wr, Wv, Wk, Wq, WrB, WvT, WkT, WqT);
  prep_vectors<<<dim3(4), 512, 0, stream>>>(Wk, Wq, Wr, bv, bk, bq, wv_, v2, u3, beta);

  // U = Wr*Wv, VT = Wq^T*Wk
  gemm_nt<EPI_BOTH><<<dim3(4, 4, 1), 256, 0, stream>>>(
      WrB, WvT, Uf, Ubf, 512, 512, 512, 512, 0, 0, 0, 1, 1.f,
      nullptr, nullptr, nullptr, nullptr, nullptr);
  gemm_nt<EPI_BOTH><<<dim3(4, 4, 1), 256, 0, stream>>>(
      WqT, WkT, VTf, VTbf, 512, 512, 512, 512, 0, 0, 0, 1, 1.f,
      nullptr, nullptr, nullptr, nullptr, nullptr);

  // G_n = X_n X_n^T  (split-K=4, atomic accumulate)
  gemm_nt<EPI_ATOMIC><<<dim3(4, 4, 64), 256, 0, stream>>>(
      Xbf, Xbf, Gf, nullptr, 1024, 4096, 4096, 512,
      (long)kC * kHW, (long)kC * kHW, (long)kC * kC, 4, 1.f,
      nullptr, nullptr, nullptr, nullptr, nullptr);
  cvt_f2b<<<dim3(4096), 256, 0, stream>>>(Gf, Gbf, (int)(kN * kC * kC / 4));

  batch_vectors<<<dim3(16), 512, 0, stream>>>(Uf, VTf, Gf, sbuf, wv_, u3, beta, br,
                                              u2, v3, cvec);

  // T_n = U G_n
  gemm_nt<EPI_BF16><<<dim3(4, 4, 16), 256, 0, stream>>>(
      Ubf, Gbf, nullptr, Tbf, 512, 512, 512, 512,
      0, (long)kC * kC, (long)kC * kC, 1, 1.f,
      nullptr, nullptr, nullptr, nullptr, nullptr);

  // M_n = T_n V /HW + rank-1 terms
  gemm_nt<EPI_RANK1><<<dim3(4, 4, 16), 256, 0, stream>>>(
      Tbf, VTbf, nullptr, Mbf, 512, 512, 512, 512,
      (long)kC * kC, 0, (long)kC * kC, 1, 1.0f / 4096.0f,
      u2, v2, u3, v3, nullptr);

  // out_n = M_n X_n + c_n
  gemm_nt<EPI_OUT><<<dim3(32, 4, 16), 256, 0, stream>>>(
      Mbf, XbfT, out, nullptr, 512, 512, 512, 4096,
      (long)kC * kC, (long)kHW * kC, (long)kC * kHW, 1, 1.f,
      nullptr, nullptr, nullptr, nullptr, cvec);
}

// Round 4
// 617.987 us; speedup vs baseline: 1.8588x; 1.8588x over previous
//
#include <hip/hip_runtime.h>

typedef unsigned short ushort_t;
typedef __attribute__((ext_vector_type(8))) short bf16x8;
typedef __attribute__((ext_vector_type(4))) float f32x4;

static constexpr long kN = 16, kC = 512, kHW = 4096;

// ---- workspace layout (bytes) ----
static constexpr size_t OFF_XBF  = 0;
static constexpr size_t OFF_XBFT = OFF_XBF  + (size_t)kN*kC*kHW*2;   // 64 MiB
static constexpr size_t OFF_S    = OFF_XBFT + (size_t)kN*kC*kHW*2;   // 128 MiB
static constexpr size_t OFF_WRB  = OFF_S    + (size_t)kN*kC*4;
static constexpr size_t OFF_WVT  = OFF_WRB  + (size_t)kC*kC*2;
static constexpr size_t OFF_WKT  = OFF_WVT  + (size_t)kC*kC*2;
static constexpr size_t OFF_WQT  = OFF_WKT  + (size_t)kC*kC*2;
static constexpr size_t OFF_wv   = OFF_WQT  + (size_t)kC*kC*2;
static constexpr size_t OFF_v2   = OFF_wv   + 2048;
static constexpr size_t OFF_u3   = OFF_v2   + 2048;
static constexpr size_t OFF_beta = OFF_u3   + 2048;
static constexpr size_t OFF_U    = OFF_beta + 256;
static constexpr size_t OFF_UBF  = OFF_U    + (size_t)kC*kC*4;
static constexpr size_t OFF_VT   = OFF_UBF  + (size_t)kC*kC*2;
static constexpr size_t OFF_VTBF = OFF_VT   + (size_t)kC*kC*4;
static constexpr size_t OFF_G    = OFF_VTBF + (size_t)kC*kC*2;
static constexpr size_t OFF_GBF  = OFF_G    + (size_t)kN*kC*kC*4;
static constexpr size_t OFF_TBF  = OFF_GBF  + (size_t)kN*kC*kC*2;
static constexpr size_t OFF_MBF  = OFF_TBF  + (size_t)kN*kC*kC*2;
static constexpr size_t OFF_u2   = OFF_MBF  + (size_t)kN*kC*kC*2;
static constexpr size_t OFF_v3   = OFF_u2   + (size_t)kN*kC*4;
static constexpr size_t OFF_c    = OFF_v3   + (size_t)kN*kC*4;
static constexpr size_t OFF_G1   = OFF_c    + (size_t)kN*kC*4;
static constexpr size_t OFF_SW   = OFF_G1   + (size_t)kN*kC*4;

static __device__ __forceinline__ ushort_t f2bf(float f) {
  union { float f; unsigned u; } x; x.f = f;
  unsigned r = x.u + 0x7fffu + ((x.u >> 16) & 1u);
  return (ushort_t)(r >> 16);
}

static __device__ __forceinline__ float wred(float a) {
  a += __shfl_xor(a, 32); a += __shfl_xor(a, 16); a += __shfl_xor(a, 8);
  a += __shfl_xor(a, 4);  a += __shfl_xor(a, 2);  a += __shfl_xor(a, 1);
  return a;
}

#define ASYNC16(g, l) __builtin_amdgcn_global_load_lds( \
    (const __attribute__((address_space(1))) void*)(g), \
    (__attribute__((address_space(3))) void*)(l), 16, 0, 0)

// ---- X fp32 -> Xbf [C][HW], XbfT [HW][C] (bf16), row sums s ----
__global__ __launch_bounds__(256) void cvt_kernel(
    const float* __restrict__ X, ushort_t* __restrict__ Xbf,
    ushort_t* __restrict__ XbfT, float* __restrict__ s) {
  __shared__ ushort_t tile[64][80];
  const int n = blockIdx.z, cb = blockIdx.y << 6, mb = blockIdx.x << 6;
  const int t = threadIdx.x;
  const int r = t >> 2, c0 = (t & 3) << 4;
  const long base = ((long)(n * 512 + cb + r)) << 12;  // *4096
  const float4* sp = (const float4*)(X + base + mb + c0);
  __align__(16) float fb[16];
  *(float4*)&fb[0]  = sp[0]; *(float4*)&fb[4]  = sp[1];
  *(float4*)&fb[8]  = sp[2]; *(float4*)&fb[12] = sp[3];
  float sum = 0.f;
  __align__(16) ushort_t ub[16];
#pragma unroll
  for (int e = 0; e < 16; ++e) { sum += fb[e]; ub[e] = f2bf(fb[e]); }
  sum += __shfl_xor(sum, 1); sum += __shfl_xor(sum, 2);
  if ((t & 3) == 0) atomicAdd(&s[n * 512 + cb + r], sum);
  ushort_t* dX = Xbf + base + mb + c0;
  *(uint4*)dX = *(const uint4*)&ub[0];
  *(uint4*)(dX + 8) = *(const uint4*)&ub[8];
  *(uint4*)&tile[r][c0] = *(const uint4*)&ub[0];
  *(uint4*)&tile[r][c0 + 8] = *(const uint4*)&ub[8];
  __syncthreads();
  const int mr = t >> 2, cc = (t & 3) << 4;
  __align__(16) ushort_t ob[16];
#pragma unroll
  for (int i = 0; i < 16; ++i) ob[i] = tile[cc + i][mr];
  ushort_t* dT = XbfT + ((long)n * 4096 + mb + mr) * 512 + cb + cc;
  *(uint4*)dT = *(const uint4*)&ob[0];
  *(uint4*)(dT + 8) = *(const uint4*)&ob[8];
}

// ---- weights: Wr->bf16 copy; Wv,Wk,Wq -> transposed bf16 ----
__global__ __launch_bounds__(256) void prep_weights(
    const float* __restrict__ Wr, const float* __restrict__ Wv,
    const float* __restrict__ Wk, const float* __restrict__ Wq,
    ushort_t* __restrict__ WrB, ushort_t* __restrict__ WvT,
    ushort_t* __restrict__ WkT, ushort_t* __restrict__ WqT) {
  __shared__ float tile[64][65];
  const int z = blockIdx.z, t = threadIdx.x;
  const float* src = (z == 0) ? Wr : (z == 1) ? Wv : (z == 2) ? Wk : Wq;
  ushort_t* dst    = (z == 0) ? WrB : (z == 1) ? WvT : (z == 2) ? WkT : WqT;
  const int r = t >> 2, c0 = (t & 3) << 4;
  const int gr = (blockIdx.y << 6) + r, gc0 = (blockIdx.x << 6) + c0;
  const float4* sp = (const float4*)(src + gr * 512 + gc0);
  __align__(16) float fb[16];
  *(float4*)&fb[0]  = sp[0]; *(float4*)&fb[4]  = sp[1];
  *(float4*)&fb[8]  = sp[2]; *(float4*)&fb[12] = sp[3];
  if (z == 0) {
    __align__(16) ushort_t ub[16];
#pragma unroll
    for (int e = 0; e < 16; ++e) ub[e] = f2bf(fb[e]);
    ushort_t* d = dst + gr * 512 + gc0;
    *(uint4*)d = *(const uint4*)&ub[0];
    *(uint4*)(d + 8) = *(const uint4*)&ub[8];
  } else {
#pragma unroll
    for (int e = 0; e < 16; ++e) tile[r][c0 + e] = fb[e];
    __syncthreads();
    const int mr = t >> 2, k0 = (t & 3) << 4;
    __align__(16) ushort_t ub[16];
#pragma unroll
    for (int i = 0; i < 16; ++i) ub[i] = f2bf(tile[k0 + i][mr]);
    ushort_t* d = dst + ((blockIdx.x << 6) + mr) * 512 + (blockIdx.y << 6) + k0;
    *(uint4*)d = *(const uint4*)&ub[0];
    *(uint4*)(d + 8) = *(const uint4*)&ub[8];
  }
}

// ---- fixed vectors: w = Wk^T bq, v2 = Wq^T bk, u3 = Wr bv, beta = bk.bq ----
__global__ __launch_bounds__(512) void prep_vectors(
    const float* __restrict__ Wk, const float* __restrict__ Wq,
    const float* __restrict__ Wr, const float* __restrict__ bv,
    const float* __restrict__ bk, const float* __restrict__ bq,
    float* __restrict__ w, float* __restrict__ v2,
    float* __restrict__ u3, float* __restrict__ beta) {
  const int z = blockIdx.x, t = threadIdx.x;
  if (z == 0) {
    float a = 0; for (int k = 0; k < 512; ++k) a += Wk[k * 512 + t] * bq[k];
    w[t] = a;
  } else if (z == 1) {
    float a = 0; for (int k = 0; k < 512; ++k) a += Wq[k * 512 + t] * bk[k];
    v2[t] = a;
  } else if (z == 2) {
    float a = 0; for (int k = 0; k < 512; ++k) a += Wr[t * 512 + k] * bv[k];
    u3[t] = a;
  } else {
    __shared__ float red[512];
    red[t] = bk[t] * bq[t];
    __syncthreads();
    for (int st = 256; st; st >>= 1) { if (t < st) red[t] += red[t + st]; __syncthreads(); }
    if (t == 0) beta[0] = red[0];
  }
}

// ---- vecA: one wave per row-task ----
// tasks 0..24575: rid -> n = rid/1536, r = rid%1536
//   task r>>9: 0: u2[n,row]=U[row].s_n  1: v3[n,row]=VT[row].s_n  2: g1[n,row]=G_n[row].w
// tasks 24576..24591: sw[n] = s_n . w
__global__ __launch_bounds__(256) void vecA(
    const float* __restrict__ U, const float* __restrict__ VT,
    const float* __restrict__ G, const float* __restrict__ s,
    const float* __restrict__ w,
    float* __restrict__ u2, float* __restrict__ v3,
    float* __restrict__ g1, float* __restrict__ sw) {
  const int rid = (blockIdx.x << 2) + (threadIdx.x >> 6);
  const int ln = threadIdx.x & 63;
  const float4* mat;
  const float4* vec;
  if (rid < 24576) {
    const int n = rid / 1536, r = rid - n * 1536;
    const int task = r >> 9, row = r & 511;
    if (task == 0)      { mat = (const float4*)(U  + row * 512); vec = (const float4*)(s + n * 512); }
    else if (task == 1) { mat = (const float4*)(VT + row * 512); vec = (const float4*)(s + n * 512); }
    else                { mat = (const float4*)(G + ((long)n * 512 + row) * 512); vec = (const float4*)w; }
    float4 a0 = mat[ln], a1 = mat[ln + 64];
    float4 b0 = vec[ln & 127], b1 = vec[(ln + 64) & 127];
    float a = a0.x * b0.x + a0.y * b0.y + a0.z * b0.z + a0.w * b0.w
            + a1.x * b1.x + a1.y * b1.y + a1.z * b1.z + a1.w * b1.w;
    a = wred(a);
    if (ln == 0) {
      const int n512 = n * 512 + (r & 511);
      if (task == 0) u2[n512] = a;
      else if (task == 1) v3[n512] = a;
      else g1[n512] = a;
    }
  } else {
    const int n = rid - 24576;
    const float4* sn = (const float4*)(s + n * 512);
    const float4* wv = (const float4*)w;
    float4 a0 = sn[ln], a1 = sn[ln + 64];
    float4 b0 = wv[ln], b1 = wv[ln + 64];
    float a = a0.x * b0.x + a0.y * b0.y + a0.z * b0.z + a0.w * b0.w
            + a1.x * b1.x + a1.y * b1.y + a1.z * b1.z + a1.w * b1.w;
    a = wred(a);
    if (ln == 0) sw[n] = a;
  }
}

// ---- vecB: cvec[n,row] = (U[row].g1_n + beta*u2[n,row] + sw[n]*u3[row])/4096
//                          + beta*u3[row] + br[row] ----
__global__ __launch_bounds__(256) void vecB(
    const float* __restrict__ U, const float* __restrict__ g1,
    const float* __restrict__ u2, const float* __restrict__ u3,
    const float* __restrict__ sw, const float* __restrict__ beta,
    const float* __restrict__ br, float* __restrict__ cvec) {
  const int rid = (blockIdx.x << 2) + (threadIdx.x >> 6);
  const int ln = threadIdx.x & 63;
  const int n = rid >> 9, row = rid & 511;
  const float4* mat = (const float4*)(U + row * 512);
  const float4* vec = (const float4*)(g1 + n * 512);
  float4 a0 = mat[ln], a1 = mat[ln + 64];
  float4 b0 = vec[ln], b1 = vec[ln + 64];
  float a = a0.x * b0.x + a0.y * b0.y + a0.z * b0.z + a0.w * b0.w
          + a1.x * b1.x + a1.y * b1.y + a1.z * b1.z + a1.w * b1.w;
  a = wred(a);
  if (ln == 0) {
    const float bet = beta[0];
    cvec[n * 512 + row] = (a + bet * u2[n * 512 + row] + sw[n] * u3[row]) * (1.0f / 4096.0f)
                          + bet * u3[row] + br[row];
  }
}

// ---- fp32 -> bf16 elementwise ----
__global__ __launch_bounds__(256) void cvt_f2b(
    const float* __restrict__ src, ushort_t* __restrict__ dst, int n4) {
  const int i = blockIdx.x * 256 + threadIdx.x;
  if (i >= n4) return;
  const float4 v = ((const float4*)src)[i];
  union { ushort_t u[4]; uint2 q; } o;
  o.u[0] = f2bf(v.x); o.u[1] = f2bf(v.y); o.u[2] = f2bf(v.z); o.u[3] = f2bf(v.w);
  ((uint2*)dst)[i] = o.q;
}

// ---- generic NT GEMM: D[i,j] = sum_k A[i,k]*B[j,k], 128x128x64 tiles ----
enum { EPI_BOTH = 0, EPI_ATOMIC = 1, EPI_BF16 = 2, EPI_RANK1 = 3, EPI_OUT = 4 };

template <int EPI>
__global__ __launch_bounds__(256) void gemm_nt(
    const ushort_t* __restrict__ A, const ushort_t* __restrict__ B,
    float* __restrict__ outF, ushort_t* __restrict__ outB,
    int K, int lda, int ldb, int ldc,
    long sA, long sB, long sC, int kchunks, float alpha,
    const float* __restrict__ eu2, const float* __restrict__ ev2,
    const float* __restrict__ eu3, const float* __restrict__ ev3,
    const float* __restrict__ ec) {
  __shared__ __align__(16) ushort_t As[128 * 64];
  __shared__ __align__(16) ushort_t Bs[128 * 64];
  const int z = blockIdx.z;
  const int batch = z / kchunks, kc = z - batch * kchunks;
  const int bm = blockIdx.y << 7, bn = blockIdx.x << 7;
  const ushort_t* Ab = A + (long)batch * sA + (long)bm * lda + (long)kc * K;
  const ushort_t* Bb = B + (long)batch * sB + (long)bn * ldb + (long)kc * K;
  const int tid = threadIdx.x;
  const int wave = tid >> 6, lane = tid & 63;
  const int wr = wave >> 1, wc = wave & 1;
  const int srow = lane >> 3;
  const int scol = (lane & 7) << 3;
  f32x4 acc[4][4];
  const f32x4 z4 = {0.f, 0.f, 0.f, 0.f};
#pragma unroll
  for (int i = 0; i < 4; ++i)
#pragma unroll
    for (int j = 0; j < 4; ++j) acc[i][j] = z4;

  for (int kt = 0; kt < K; kt += 64) {
#pragma unroll
    for (int p = 0; p < 4; ++p) {
      const int rbase = (p << 5) + (wave << 3);
      ASYNC16(Ab + (long)(rbase + srow) * lda + kt + scol, &As[rbase << 6]);
      ASYNC16(Bb + (long)(rbase + srow) * ldb + kt + scol, &Bs[rbase << 6]);
    }
    __syncthreads();
    const int fr = lane & 15, kg = lane >> 4;
#pragma unroll
    for (int ks = 0; ks < 2; ++ks) {
      bf16x8 av[4], bv[4];
#pragma unroll
      for (int i = 0; i < 4; ++i)
        av[i] = *(const bf16x8*)&As[((wr << 6) + (i << 4) + fr) * 64 + (ks << 5) + (kg << 3)];
#pragma unroll
      for (int j = 0; j < 4; ++j)
        bv[j] = *(const bf16x8*)&Bs[((wc << 6) + (j << 4) + fr) * 64 + (ks << 5) + (kg << 3)];
#pragma unroll
      for (int i = 0; i < 4; ++i)
#pragma unroll
        for (int j = 0; j < 4; ++j)
          acc[i][j] = __builtin_amdgcn_mfma_f32_16x16x32_bf16(av[i], bv[j], acc[i][j], 0, 0, 0);
    }
    __syncthreads();
  }

  const int fr = lane & 15, rg = lane >> 4;
  const float* eu2b = (EPI == EPI_RANK1) ? eu2 + (batch << 9) : nullptr;
  const float* ev3b = (EPI == EPI_RANK1) ? ev3 + (batch << 9) : nullptr;
  const float* ecb  = (EPI == EPI_OUT)   ? ec  + (batch << 9) : nullptr;
#pragma unroll
  for (int i = 0; i < 4; ++i) {
#pragma unroll
    for (int j = 0; j < 4; ++j) {
      const int col = bn + (wc << 6) + (j << 4) + fr;
#pragma unroll
      for (int q = 0; q < 4; ++q) {
        const int row = bm + (wr << 6) + (i << 4) + (rg << 2) + q;
        float val = acc[i][j][q];
        const long off = (long)batch * sC + (long)row * ldc + col;
        if (EPI == EPI_ATOMIC) {
          atomicAdd(&outF[off], val);
        } else if (EPI == EPI_BOTH) {
          outF[off] = val; outB[off] = f2bf(val);
        } else if (EPI == EPI_BF16) {
          outB[off] = f2bf(val);
        } else if (EPI == EPI_RANK1) {
          val = val * alpha + (eu2b[row] * ev2[col] + eu3[row] * ev3b[col]) * alpha
                + eu3[row] * ev2[col];
          outB[off] = f2bf(val);
        } else {
          outF[off] = val + ecb[row];
        }
      }
    }
  }
}

extern "C" void kernel_launch(void* const* d_in, const int* in_sizes, int n_in,
                              void* d_out, int out_size, void* d_ws, size_t ws_size,
                              hipStream_t stream) {
  const float* X  = (const float*)d_in[0];
  const float* Wv = (const float*)d_in[1];
  const float* bv = (const float*)d_in[2];
  const float* Wk = (const float*)d_in[3];
  const float* bk = (const float*)d_in[4];
  const float* Wq = (const float*)d_in[5];
  const float* bq = (const float*)d_in[6];
  const float* Wr = (const float*)d_in[7];
  const float* br = (const float*)d_in[8];
  float* out = (float*)d_out;
  char* ws = (char*)d_ws;

  ushort_t* Xbf  = (ushort_t*)(ws + OFF_XBF);
  ushort_t* XbfT = (ushort_t*)(ws + OFF_XBFT);
  float*    sbuf = (float*)(ws + OFF_S);
  ushort_t* WrB  = (ushort_t*)(ws + OFF_WRB);
  ushort_t* WvT  = (ushort_t*)(ws + OFF_WVT);
  ushort_t* WkT  = (ushort_t*)(ws + OFF_WKT);
  ushort_t* WqT  = (ushort_t*)(ws + OFF_WQT);
  float*    wv_  = (float*)(ws + OFF_wv);
  float*    v2   = (float*)(ws + OFF_v2);
  float*    u3   = (float*)(ws + OFF_u3);
  float*    beta = (float*)(ws + OFF_beta);
  float*    Uf   = (float*)(ws + OFF_U);
  ushort_t* Ubf  = (ushort_t*)(ws + OFF_UBF);
  float*    VTf  = (float*)(ws + OFF_VT);
  ushort_t* VTbf = (ushort_t*)(ws + OFF_VTBF);
  float*    Gf   = (float*)(ws + OFF_G);
  ushort_t* Gbf  = (ushort_t*)(ws + OFF_GBF);
  ushort_t* Tbf  = (ushort_t*)(ws + OFF_TBF);
  ushort_t* Mbf  = (ushort_t*)(ws + OFF_MBF);
  float*    u2   = (float*)(ws + OFF_u2);
  float*    v3   = (float*)(ws + OFF_v3);
  float*    cvec = (float*)(ws + OFF_c);
  float*    g1   = (float*)(ws + OFF_G1);
  float*    swb  = (float*)(ws + OFF_SW);

  hipMemsetAsync(sbuf, 0, (size_t)kN * kC * 4, stream);
  hipMemsetAsync(Gf, 0, (size_t)kN * kC * kC * 4, stream);

  cvt_kernel<<<dim3(64, 8, 16), 256, 0, stream>>>(X, Xbf, XbfT, sbuf);
  prep_weights<<<dim3(8, 8, 4), 256, 0, stream>>>(Wr, Wv, Wk, Wq, WrB, WvT, WkT, WqT);
  prep_vectors<<<dim3(4), 512, 0, stream>>>(Wk, Wq, Wr, bv, bk, bq, wv_, v2, u3, beta);

  // U = Wr*Wv, VT = Wq^T*Wk
  gemm_nt<EPI_BOTH><<<dim3(4, 4, 1), 256, 0, stream>>>(
      WrB, WvT, Uf, Ubf, 512, 512, 512, 512, 0, 0, 0, 1, 1.f,
      nullptr, nullptr, nullptr, nullptr, nullptr);
  gemm_nt<EPI_BOTH><<<dim3(4, 4, 1), 256, 0, stream>>>(
      WqT, WkT, VTf, VTbf, 512, 512, 512, 512, 0, 0, 0, 1, 1.f,
      nullptr, nullptr, nullptr, nullptr, nullptr);

  // G_n = X_n X_n^T  (split-K=4, atomic accumulate)
  gemm_nt<EPI_ATOMIC><<<dim3(4, 4, 64), 256, 0, stream>>>(
      Xbf, Xbf, Gf, nullptr, 1024, 4096, 4096, 512,
      (long)kC * kHW, (long)kC * kHW, (long)kC * kC, 4, 1.f,
      nullptr, nullptr, nullptr, nullptr, nullptr);
  cvt_f2b<<<dim3(4096), 256, 0, stream>>>(Gf, Gbf, (int)(kN * kC * kC / 4));

  // per-batch vectors, massively parallel
  vecA<<<dim3(6148), 256, 0, stream>>>(Uf, VTf, Gf, sbuf, wv_, u2, v3, g1, swb);
  vecB<<<dim3(2048), 256, 0, stream>>>(Uf, g1, u2, u3, swb, beta, br, cvec);

  // T_n = U G_n
  gemm_nt<EPI_BF16><<<dim3(4, 4, 16), 256, 0, stream>>>(
      Ubf, Gbf, nullptr, Tbf, 512, 512, 512, 512,
      0, (long)kC * kC, (long)kC * kC, 1, 1.f,
      nullptr, nullptr, nullptr, nullptr, nullptr);

  // M_n = T_n V /HW + rank-1 terms
  gemm_nt<EPI_RANK1><<<dim3(4, 4, 16), 256, 0, stream>>>(
      Tbf, VTbf, nullptr, Mbf, 512, 512, 512, 512,
      (long)kC * kC, 0, (long)kC * kC, 1, 1.0f / 4096.0f,
      u2, v2, u3, v3, nullptr);

  // out_n = M_n X_n + c_n
  gemm_nt<EPI_OUT><<<dim3(32, 4, 16), 256, 0, stream>>>(
      Mbf, XbfT, out, nullptr, 512, 512, 512, 4096,
      (long)kC * kC, (long)kHW * kC, (long)kC * kHW, 1, 1.f,
      nullptr, nullptr, nullptr, nullptr, cvec);
}

// Round 6
// 504.365 us; speedup vs baseline: 2.2775x; 1.2253x over previous
//
#include <hip/hip_runtime.h>

typedef unsigned short ushort_t;
typedef __attribute__((ext_vector_type(8))) short bf16x8;
typedef __attribute__((ext_vector_type(4))) float f32x4;

static constexpr long kN = 16, kC = 512, kHW = 4096;

// ---- workspace layout (bytes) ----
static constexpr size_t OFF_XBF  = 0;
static constexpr size_t OFF_XBFT = OFF_XBF  + (size_t)kN*kC*kHW*2;   // 64 MiB
static constexpr size_t OFF_S    = OFF_XBFT + (size_t)kN*kC*kHW*2;   // 128 MiB
static constexpr size_t OFF_WRB  = OFF_S    + (size_t)kN*kC*4;
static constexpr size_t OFF_WVT  = OFF_WRB  + (size_t)kC*kC*2;
static constexpr size_t OFF_WKT  = OFF_WVT  + (size_t)kC*kC*2;
static constexpr size_t OFF_WQT  = OFF_WKT  + (size_t)kC*kC*2;
static constexpr size_t OFF_wv   = OFF_WQT  + (size_t)kC*kC*2;
static constexpr size_t OFF_v2   = OFF_wv   + 2048;
static constexpr size_t OFF_u3   = OFF_v2   + 2048;
static constexpr size_t OFF_beta = OFF_u3   + 2048;
static constexpr size_t OFF_U    = OFF_beta + 256;
static constexpr size_t OFF_UBF  = OFF_U    + (size_t)kC*kC*4;
static constexpr size_t OFF_VT   = OFF_UBF  + (size_t)kC*kC*2;
static constexpr size_t OFF_VTBF = OFF_VT   + (size_t)kC*kC*4;
static constexpr size_t OFF_G    = OFF_VTBF + (size_t)kC*kC*2;
static constexpr size_t OFF_GBF  = OFF_G    + (size_t)kN*kC*kC*4;
static constexpr size_t OFF_TBF  = OFF_GBF  + (size_t)kN*kC*kC*2;
static constexpr size_t OFF_MBF  = OFF_TBF  + (size_t)kN*kC*kC*2;
static constexpr size_t OFF_u2   = OFF_MBF  + (size_t)kN*kC*kC*2;
static constexpr size_t OFF_v3   = OFF_u2   + (size_t)kN*kC*4;
static constexpr size_t OFF_c    = OFF_v3   + (size_t)kN*kC*4;
static constexpr size_t OFF_G1   = OFF_c    + (size_t)kN*kC*4;
static constexpr size_t OFF_SW   = OFF_G1   + (size_t)kN*kC*4;

static __device__ __forceinline__ ushort_t f2bf(float f) {
  union { float f; unsigned u; } x; x.f = f;
  unsigned r = x.u + 0x7fffu + ((x.u >> 16) & 1u);
  return (ushort_t)(r >> 16);
}

static __device__ __forceinline__ float wred(float a) {
  a += __shfl_xor(a, 32); a += __shfl_xor(a, 16); a += __shfl_xor(a, 8);
  a += __shfl_xor(a, 4);  a += __shfl_xor(a, 2);  a += __shfl_xor(a, 1);
  return a;
}

#define ASYNC16(g, l) __builtin_amdgcn_global_load_lds( \
    (const __attribute__((address_space(1))) void*)(g), \
    (__attribute__((address_space(3))) void*)(l), 16, 0, 0)

// ---- X fp32 -> Xbf [C][HW], XbfT [HW][C] (bf16), row sums s ----
__global__ __launch_bounds__(256) void cvt_kernel(
    const float* __restrict__ X, ushort_t* __restrict__ Xbf,
    ushort_t* __restrict__ XbfT, float* __restrict__ s) {
  __shared__ ushort_t tile[64][80];
  const int n = blockIdx.z, cb = blockIdx.y << 6, mb = blockIdx.x << 6;
  const int t = threadIdx.x;
  const int r = t >> 2, c0 = (t & 3) << 4;
  const long base = ((long)(n * 512 + cb + r)) << 12;  // *4096
  const float4* sp = (const float4*)(X + base + mb + c0);
  __align__(16) float fb[16];
  *(float4*)&fb[0]  = sp[0]; *(float4*)&fb[4]  = sp[1];
  *(float4*)&fb[8]  = sp[2]; *(float4*)&fb[12] = sp[3];
  float sum = 0.f;
  __align__(16) ushort_t ub[16];
#pragma unroll
  for (int e = 0; e < 16; ++e) { sum += fb[e]; ub[e] = f2bf(fb[e]); }
  sum += __shfl_xor(sum, 1); sum += __shfl_xor(sum, 2);
  if ((t & 3) == 0) atomicAdd(&s[n * 512 + cb + r], sum);
  ushort_t* dX = Xbf + base + mb + c0;
  *(uint4*)dX = *(const uint4*)&ub[0];
  *(uint4*)(dX + 8) = *(const uint4*)&ub[8];
  *(uint4*)&tile[r][c0] = *(const uint4*)&ub[0];
  *(uint4*)&tile[r][c0 + 8] = *(const uint4*)&ub[8];
  __syncthreads();
  const int mr = t >> 2, cc = (t & 3) << 4;
  __align__(16) ushort_t ob[16];
#pragma unroll
  for (int i = 0; i < 16; ++i) ob[i] = tile[cc + i][mr];
  ushort_t* dT = XbfT + ((long)n * 4096 + mb + mr) * 512 + cb + cc;
  *(uint4*)dT = *(const uint4*)&ob[0];
  *(uint4*)(dT + 8) = *(const uint4*)&ob[8];
}

// ---- weights: Wr->bf16 copy; Wv,Wk,Wq -> transposed bf16 ----
__global__ __launch_bounds__(256) void prep_weights(
    const float* __restrict__ Wr, const float* __restrict__ Wv,
    const float* __restrict__ Wk, const float* __restrict__ Wq,
    ushort_t* __restrict__ WrB, ushort_t* __restrict__ WvT,
    ushort_t* __restrict__ WkT, ushort_t* __restrict__ WqT) {
  __shared__ float tile[64][65];
  const int z = blockIdx.z, t = threadIdx.x;
  const float* src = (z == 0) ? Wr : (z == 1) ? Wv : (z == 2) ? Wk : Wq;
  ushort_t* dst    = (z == 0) ? WrB : (z == 1) ? WvT : (z == 2) ? WkT : WqT;
  const int r = t >> 2, c0 = (t & 3) << 4;
  const int gr = (blockIdx.y << 6) + r, gc0 = (blockIdx.x << 6) + c0;
  const float4* sp = (const float4*)(src + gr * 512 + gc0);
  __align__(16) float fb[16];
  *(float4*)&fb[0]  = sp[0]; *(float4*)&fb[4]  = sp[1];
  *(float4*)&fb[8]  = sp[2]; *(float4*)&fb[12] = sp[3];
  if (z == 0) {
    __align__(16) ushort_t ub[16];
#pragma unroll
    for (int e = 0; e < 16; ++e) ub[e] = f2bf(fb[e]);
    ushort_t* d = dst + gr * 512 + gc0;
    *(uint4*)d = *(const uint4*)&ub[0];
    *(uint4*)(d + 8) = *(const uint4*)&ub[8];
  } else {
#pragma unroll
    for (int e = 0; e < 16; ++e) tile[r][c0 + e] = fb[e];
    __syncthreads();
    const int mr = t >> 2, k0 = (t & 3) << 4;
    __align__(16) ushort_t ub[16];
#pragma unroll
    for (int i = 0; i < 16; ++i) ub[i] = f2bf(tile[k0 + i][mr]);
    ushort_t* d = dst + ((blockIdx.x << 6) + mr) * 512 + (blockIdx.y << 6) + k0;
    *(uint4*)d = *(const uint4*)&ub[0];
    *(uint4*)(d + 8) = *(const uint4*)&ub[8];
  }
}

// ---- fixed vectors, one wave per output element ----
// rid 0..511: w[j]    = sum_k Wk[k][j]*bq[k]   (column dot, lane-strided)
// rid 512..1023: v2[j] = sum_k Wq[k][j]*bk[k]  (column dot)
// rid 1024..1535: u3[t] = Wr[t,:].bv           (row dot, float4)
// rid 1536: beta = bk.bq
__global__ __launch_bounds__(256) void prep_vectors(
    const float* __restrict__ Wk, const float* __restrict__ Wq,
    const float* __restrict__ Wr, const float* __restrict__ bv,
    const float* __restrict__ bk, const float* __restrict__ bq,
    float* __restrict__ w, float* __restrict__ v2,
    float* __restrict__ u3, float* __restrict__ beta) {
  const int rid = (blockIdx.x << 2) + (threadIdx.x >> 6);
  const int ln = threadIdx.x & 63;
  if (rid < 1024) {
    const int j = rid & 511;
    const float* M = (rid < 512) ? Wk : Wq;
    const float* b = (rid < 512) ? bq : bk;
    float a = 0.f;
#pragma unroll
    for (int i = 0; i < 8; ++i) {
      const int k = ln + (i << 6);
      a += M[k * 512 + j] * b[k];
    }
    a = wred(a);
    if (ln == 0) { if (rid < 512) w[j] = a; else v2[j] = a; }
  } else if (rid < 1536) {
    const int t = rid - 1024;
    const float4* m = (const float4*)(Wr + t * 512);
    const float4* v = (const float4*)bv;
    float4 a0 = m[ln], b0 = v[ln], a1 = m[ln + 64], b1 = v[ln + 64];
    float a = a0.x * b0.x + a0.y * b0.y + a0.z * b0.z + a0.w * b0.w
            + a1.x * b1.x + a1.y * b1.y + a1.z * b1.z + a1.w * b1.w;
    a = wred(a);
    if (ln == 0) u3[t] = a;
  } else if (rid == 1536) {
    const float4* x = (const float4*)bk;
    const float4* y = (const float4*)bq;
    float4 a0 = x[ln], b0 = y[ln], a1 = x[ln + 64], b1 = y[ln + 64];
    float a = a0.x * b0.x + a0.y * b0.y + a0.z * b0.z + a0.w * b0.w
            + a1.x * b1.x + a1.y * b1.y + a1.z * b1.z + a1.w * b1.w;
    a = wred(a);
    if (ln == 0) beta[0] = a;
  }
}

// ---- vecA: one wave per row-task ----
// tasks 0..24575: rid -> n = rid/1536, r = rid%1536
//   task r>>9: 0: u2[n,row]=U[row].s_n  1: v3[n,row]=VT[row].s_n  2: g1[n,row]=G_n[row].w
// tasks 24576..24591: sw[n] = s_n . w
__global__ __launch_bounds__(256) void vecA(
    const float* __restrict__ U, const float* __restrict__ VT,
    const float* __restrict__ G, const float* __restrict__ s,
    const float* __restrict__ w,
    float* __restrict__ u2, float* __restrict__ v3,
    float* __restrict__ g1, float* __restrict__ sw) {
  const int rid = (blockIdx.x << 2) + (threadIdx.x >> 6);
  const int ln = threadIdx.x & 63;
  const float4* mat;
  const float4* vec;
  if (rid < 24576) {
    const int n = rid / 1536, r = rid - n * 1536;
    const int task = r >> 9, row = r & 511;
    if (task == 0)      { mat = (const float4*)(U  + row * 512); vec = (const float4*)(s + n * 512); }
    else if (task == 1) { mat = (const float4*)(VT + row * 512); vec = (const float4*)(s + n * 512); }
    else                { mat = (const float4*)(G + ((long)n * 512 + row) * 512); vec = (const float4*)w; }
    float4 a0 = mat[ln], a1 = mat[ln + 64];
    float4 b0 = vec[ln & 127], b1 = vec[(ln + 64) & 127];
    float a = a0.x * b0.x + a0.y * b0.y + a0.z * b0.z + a0.w * b0.w
            + a1.x * b1.x + a1.y * b1.y + a1.z * b1.z + a1.w * b1.w;
    a = wred(a);
    if (ln == 0) {
      const int n512 = n * 512 + (r & 511);
      if (task == 0) u2[n512] = a;
      else if (task == 1) v3[n512] = a;
      else g1[n512] = a;
    }
  } else {
    const int n = rid - 24576;
    const float4* sn = (const float4*)(s + n * 512);
    const float4* wv = (const float4*)w;
    float4 a0 = sn[ln], a1 = sn[ln + 64];
    float4 b0 = wv[ln], b1 = wv[ln + 64];
    float a = a0.x * b0.x + a0.y * b0.y + a0.z * b0.z + a0.w * b0.w
            + a1.x * b1.x + a1.y * b1.y + a1.z * b1.z + a1.w * b1.w;
    a = wred(a);
    if (ln == 0) sw[n] = a;
  }
}

// ---- vecB: cvec[n,row] = (U[row].g1_n + beta*u2[n,row] + sw[n]*u3[row])/4096
//                          + beta*u3[row] + br[row] ----
__global__ __launch_bounds__(256) void vecB(
    const float* __restrict__ U, const float* __restrict__ g1,
    const float* __restrict__ u2, const float* __restrict__ u3,
    const float* __restrict__ sw, const float* __restrict__ beta,
    const float* __restrict__ br, float* __restrict__ cvec) {
  const int rid = (blockIdx.x << 2) + (threadIdx.x >> 6);
  const int ln = threadIdx.x & 63;
  const int n = rid >> 9, row = rid & 511;
  const float4* mat = (const float4*)(U + row * 512);
  const float4* vec = (const float4*)(g1 + n * 512);
  float4 a0 = mat[ln], a1 = mat[ln + 64];
  float4 b0 = vec[ln], b1 = vec[ln + 64];
  float a = a0.x * b0.x + a0.y * b0.y + a0.z * b0.z + a0.w * b0.w
          + a1.x * b1.x + a1.y * b1.y + a1.z * b1.z + a1.w * b1.w;
  a = wred(a);
  if (ln == 0) {
    const float bet = beta[0];
    cvec[n * 512 + row] = (a + bet * u2[n * 512 + row] + sw[n] * u3[row]) * (1.0f / 4096.0f)
                          + bet * u3[row] + br[row];
  }
}

// ---- fp32 -> bf16 elementwise ----
__global__ __launch_bounds__(256) void cvt_f2b(
    const float* __restrict__ src, ushort_t* __restrict__ dst, int n4) {
  const int i = blockIdx.x * 256 + threadIdx.x;
  if (i >= n4) return;
  const float4 v = ((const float4*)src)[i];
  union { ushort_t u[4]; uint2 q; } o;
  o.u[0] = f2bf(v.x); o.u[1] = f2bf(v.y); o.u[2] = f2bf(v.z); o.u[3] = f2bf(v.w);
  ((uint2*)dst)[i] = o.q;
}

// ---- generic NT GEMM: D[i,j] = sum_k A[i,k]*B[j,k], 128x128x64 tiles ----
enum { EPI_BOTH = 0, EPI_ATOMIC = 1, EPI_BF16 = 2, EPI_RANK1 = 3, EPI_OUT = 4 };

template <int EPI>
__global__ __launch_bounds__(256) void gemm_nt(
    const ushort_t* __restrict__ A, const ushort_t* __restrict__ B,
    float* __restrict__ outF, ushort_t* __restrict__ outB,
    int K, int lda, int ldb, int ldc,
    long sA, long sB, long sC, int kchunks, float alpha,
    const float* __restrict__ eu2, const float* __restrict__ ev2,
    const float* __restrict__ eu3, const float* __restrict__ ev3,
    const float* __restrict__ ec) {
  __shared__ __align__(16) ushort_t As[128 * 64];
  __shared__ __align__(16) ushort_t Bs[128 * 64];
  const int z = blockIdx.z;
  const int batch = z / kchunks, kc = z - batch * kchunks;
  const int bm = blockIdx.y << 7, bn = blockIdx.x << 7;
  const ushort_t* Ab = A + (long)batch * sA + (long)bm * lda + (long)kc * K;
  const ushort_t* Bb = B + (long)batch * sB + (long)bn * ldb + (long)kc * K;
  const int tid = threadIdx.x;
  const int wave = tid >> 6, lane = tid & 63;
  const int wr = wave >> 1, wc = wave & 1;
  const int srow = lane >> 3;
  const int scol = (lane & 7) << 3;
  f32x4 acc[4][4];
  const f32x4 z4 = {0.f, 0.f, 0.f, 0.f};
#pragma unroll
  for (int i = 0; i < 4; ++i)
#pragma unroll
    for (int j = 0; j < 4; ++j) acc[i][j] = z4;

  for (int kt = 0; kt < K; kt += 64) {
#pragma unroll
    for (int p = 0; p < 4; ++p) {
      const int rbase = (p << 5) + (wave << 3);
      ASYNC16(Ab + (long)(rbase + srow) * lda + kt + scol, &As[rbase << 6]);
      ASYNC16(Bb + (long)(rbase + srow) * ldb + kt + scol, &Bs[rbase << 6]);
    }
    __syncthreads();
    const int fr = lane & 15, kg = lane >> 4;
#pragma unroll
    for (int ks = 0; ks < 2; ++ks) {
      bf16x8 av[4], bv[4];
#pragma unroll
      for (int i = 0; i < 4; ++i)
        av[i] = *(const bf16x8*)&As[((wr << 6) + (i << 4) + fr) * 64 + (ks << 5) + (kg << 3)];
#pragma unroll
      for (int j = 0; j < 4; ++j)
        bv[j] = *(const bf16x8*)&Bs[((wc << 6) + (j << 4) + fr) * 64 + (ks << 5) + (kg << 3)];
#pragma unroll
      for (int i = 0; i < 4; ++i)
#pragma unroll
        for (int j = 0; j < 4; ++j)
          acc[i][j] = __builtin_amdgcn_mfma_f32_16x16x32_bf16(av[i], bv[j], acc[i][j], 0, 0, 0);
    }
    __syncthreads();
  }

  const int fr = lane & 15, rg = lane >> 4;
  const float* eu2b = (EPI == EPI_RANK1) ? eu2 + (batch << 9) : nullptr;
  const float* ev3b = (EPI == EPI_RANK1) ? ev3 + (batch << 9) : nullptr;
  const float* ecb  = (EPI == EPI_OUT)   ? ec  + (batch << 9) : nullptr;
#pragma unroll
  for (int i = 0; i < 4; ++i) {
#pragma unroll
    for (int j = 0; j < 4; ++j) {
      const int col = bn + (wc << 6) + (j << 4) + fr;
#pragma unroll
      for (int q = 0; q < 4; ++q) {
        const int row = bm + (wr << 6) + (i << 4) + (rg << 2) + q;
        float val = acc[i][j][q];
        const long off = (long)batch * sC + (long)row * ldc + col;
        if (EPI == EPI_ATOMIC) {
          atomicAdd(&outF[off], val);
        } else if (EPI == EPI_BOTH) {
          outF[off] = val; outB[off] = f2bf(val);
        } else if (EPI == EPI_BF16) {
          outB[off] = f2bf(val);
        } else if (EPI == EPI_RANK1) {
          val = val * alpha + (eu2b[row] * ev2[col] + eu3[row] * ev3b[col]) * alpha
                + eu3[row] * ev2[col];
          outB[off] = f2bf(val);
        } else {
          outF[off] = val + ecb[row];
        }
      }
    }
  }
}

extern "C" void kernel_launch(void* const* d_in, const int* in_sizes, int n_in,
                              void* d_out, int out_size, void* d_ws, size_t ws_size,
                              hipStream_t stream) {
  const float* X  = (const float*)d_in[0];
  const float* Wv = (const float*)d_in[1];
  const float* bv = (const float*)d_in[2];
  const float* Wk = (const float*)d_in[3];
  const float* bk = (const float*)d_in[4];
  const float* Wq = (const float*)d_in[5];
  const float* bq = (const float*)d_in[6];
  const float* Wr = (const float*)d_in[7];
  const float* br = (const float*)d_in[8];
  float* out = (float*)d_out;
  char* ws = (char*)d_ws;

  ushort_t* Xbf  = (ushort_t*)(ws + OFF_XBF);
  ushort_t* XbfT = (ushort_t*)(ws + OFF_XBFT);
  float*    sbuf = (float*)(ws + OFF_S);
  ushort_t* WrB  = (ushort_t*)(ws + OFF_WRB);
  ushort_t* WvT  = (ushort_t*)(ws + OFF_WVT);
  ushort_t* WkT  = (ushort_t*)(ws + OFF_WKT);
  ushort_t* WqT  = (ushort_t*)(ws + OFF_WQT);
  float*    wv_  = (float*)(ws + OFF_wv);
  float*    v2   = (float*)(ws + OFF_v2);
  float*    u3   = (float*)(ws + OFF_u3);
  float*    beta = (float*)(ws + OFF_beta);
  float*    Uf   = (float*)(ws + OFF_U);
  ushort_t* Ubf  = (ushort_t*)(ws + OFF_UBF);
  float*    VTf  = (float*)(ws + OFF_VT);
  ushort_t* VTbf = (ushort_t*)(ws + OFF_VTBF);
  float*    Gf   = (float*)(ws + OFF_G);
  ushort_t* Gbf  = (ushort_t*)(ws + OFF_GBF);
  ushort_t* Tbf  = (ushort_t*)(ws + OFF_TBF);
  ushort_t* Mbf  = (ushort_t*)(ws + OFF_MBF);
  float*    u2   = (float*)(ws + OFF_u2);
  float*    v3   = (float*)(ws + OFF_v3);
  float*    cvec = (float*)(ws + OFF_c);
  float*    g1   = (float*)(ws + OFF_G1);
  float*    swb  = (float*)(ws + OFF_SW);

  hipMemsetAsync(sbuf, 0, (size_t)kN * kC * 4, stream);
  hipMemsetAsync(Gf, 0, (size_t)kN * kC * kC * 4, stream);

  cvt_kernel<<<dim3(64, 8, 16), 256, 0, stream>>>(X, Xbf, XbfT, sbuf);
  prep_weights<<<dim3(8, 8, 4), 256, 0, stream>>>(Wr, Wv, Wk, Wq, WrB, WvT, WkT, WqT);
  prep_vectors<<<dim3(385), 256, 0, stream>>>(Wk, Wq, Wr, bv, bk, bq, wv_, v2, u3, beta);

  // U = Wr*Wv, VT = Wq^T*Wk
  gemm_nt<EPI_BOTH><<<dim3(4, 4, 1), 256, 0, stream>>>(
      WrB, WvT, Uf, Ubf, 512, 512, 512, 512, 0, 0, 0, 1, 1.f,
      nullptr, nullptr, nullptr, nullptr, nullptr);
  gemm_nt<EPI_BOTH><<<dim3(4, 4, 1), 256, 0, stream>>>(
      WqT, WkT, VTf, VTbf, 512, 512, 512, 512, 0, 0, 0, 1, 1.f,
      nullptr, nullptr, nullptr, nullptr, nullptr);

  // G_n = X_n X_n^T  (split-K=4, atomic accumulate)
  gemm_nt<EPI_ATOMIC><<<dim3(4, 4, 64), 256, 0, stream>>>(
      Xbf, Xbf, Gf, nullptr, 1024, 4096, 4096, 512,
      (long)kC * kHW, (long)kC * kHW, (long)kC * kC, 4, 1.f,
      nullptr, nullptr, nullptr, nullptr, nullptr);
  cvt_f2b<<<dim3(4096), 256, 0, stream>>>(Gf, Gbf, (int)(kN * kC * kC / 4));

  // per-batch vectors, massively parallel
  vecA<<<dim3(6148), 256, 0, stream>>>(Uf, VTf, Gf, sbuf, wv_, u2, v3, g1, swb);
  vecB<<<dim3(2048), 256, 0, stream>>>(Uf, g1, u2, u3, swb, beta, br, cvec);

  // T_n = U G_n
  gemm_nt<EPI_BF16><<<dim3(4, 4, 16), 256, 0, stream>>>(
      Ubf, Gbf, nullptr, Tbf, 512, 512, 512, 512,
      0, (long)kC * kC, (long)kC * kC, 1, 1.f,
      nullptr, nullptr, nullptr, nullptr, nullptr);

  // M_n = T_n V /HW + rank-1 terms
  gemm_nt<EPI_RANK1><<<dim3(4, 4, 16), 256, 0, stream>>>(
      Tbf, VTbf, nullptr, Mbf, 512, 512, 512, 512,
      (long)kC * kC, 0, (long)kC * kC, 1, 1.0f / 4096.0f,
      u2, v2, u3, v3, nullptr);

  // out_n = M_n X_n + c_n
  gemm_nt<EPI_OUT><<<dim3(32, 4, 16), 256, 0, stream>>>(
      Mbf, XbfT, out, nullptr, 512, 512, 512, 4096,
      (long)kC * kC, (long)kHW * kC, (long)kC * kHW, 1, 1.f,
      nullptr, nullptr, nullptr, nullptr, cvec);
}